// Round 1
// 70.587 us; speedup vs baseline: 1.0244x; 1.0244x over previous
//
#include <hip/hip_runtime.h>

// Problem dims (compile-time constants from the reference)
#define BB 512
#define HH 32
#define LL 7
#define SS 5
#define OO 8
#define NN (BB * HH)          // 16384 independent cells
#define DIST_THRESHOLD 0.1f

typedef float f4 __attribute__((ext_vector_type(4)));
typedef float f2 __attribute__((ext_vector_type(2)));

// One thread per (n, l) pair, 8 lanes per n (lane l==7 idle -> contributes 0).
// 131072 threads = 512 blocks x 256 threads = 2 blocks/CU.
__global__ __launch_bounds__(256)
void PrimitiveCollisionCost_19533511262442_kernel(
    const float* __restrict__ pos,    // [N,L,3]
    const float* __restrict__ rot,    // [N,L,3,3]
    const float* __restrict__ off,    // [L,S,3]
    const float* __restrict__ srad,   // [L,S]
    const float* __restrict__ oc,     // [O,3]
    const float* __restrict__ orad,   // [O]
    const float* __restrict__ weight, // [1]
    float* __restrict__ out)          // [N]
{
    const int t = blockIdx.x * blockDim.x + threadIdx.x;
    const int n = t >> 3;        // cell index
    const int l = t & 7;         // link index (7 == idle lane)

    float dist = 0.0f;

    if (l < LL) {
        const float* posn = pos + (size_t)n * (LL * 3) + l * 3;
        const float* rotn = rot + (size_t)n * (LL * 9) + l * 9;

        // Vectorized loads: 12 dword loads -> 5 load instructions.
        // CDNA global loads support dword (4B) alignment for x2/x4 widths.
        const f2    p01 = *(const f2*)(posn);      // px py
        const float pz  = posn[2];
        const f4    ra  = *(const f4*)(rotn);      // r00 r01 r02 r10
        const f4    rb  = *(const f4*)(rotn + 4);  // r11 r12 r20 r21
        const float r22 = rotn[8];

        const float px = p01.x, py = p01.y;
        const float r00 = ra.x, r01 = ra.y, r02 = ra.z, r10 = ra.w;
        const float r11 = rb.x, r12 = rb.y, r20 = rb.z, r21 = rb.w;

        // All 5 world-frame sphere centers up front (independent FMAs).
        float cx[SS], cy[SS], cz[SS], rs[SS];
#pragma unroll
        for (int s = 0; s < SS; ++s) {
            const float ox = off[(l * SS + s) * 3 + 0];
            const float oy = off[(l * SS + s) * 3 + 1];
            const float oz = off[(l * SS + s) * 3 + 2];
            rs[s] = srad[l * SS + s];
            cx[s] = r00 * ox + r01 * oy + r02 * oz + px;
            cy[s] = r10 * ox + r11 * oy + r12 * oz + py;
            cz[s] = r20 * ox + r21 * oy + r22 * oz + pz;
        }

        // 5 independent max chains (fmax reordering is bit-exact).
        float best[SS];
#pragma unroll
        for (int s = 0; s < SS; ++s) best[s] = -1e30f;

#pragma unroll
        for (int o = 0; o < OO; ++o) {
            // oc/orad addresses are wave-uniform -> compiler emits s_load.
            const float ocx = oc[o * 3 + 0];
            const float ocy = oc[o * 3 + 1];
            const float ocz = oc[o * 3 + 2];
            const float ro  = orad[o];
#pragma unroll
            for (int s = 0; s < SS; ++s) {
                const float dx = cx[s] - ocx;
                const float dy = cy[s] - ocy;
                const float dz = cz[s] - ocz;
                // raw v_sqrt_f32 (<=1 ulp) instead of the IEEE ocml sequence
                const float d  = __builtin_amdgcn_sqrtf(dx * dx + dy * dy + dz * dz);
                // keep the reference association: (rs + orad[o]) - d
                best[s] = fmaxf(best[s], (rs[s] + ro) - d);
            }
        }

        float b = best[0];
#pragma unroll
        for (int s = 1; s < SS; ++s) b = fmaxf(b, best[s]);

        // clip(b + 0.1, 0, 0.2) / 0.25
        dist = fminf(fmaxf(b + DIST_THRESHOLD, 0.0f), 0.2f) * 4.0f;
    }

    // Sum the 7 link costs across the 8-lane group (xor butterfly stays
    // within the group for masks < 8).
    dist += __shfl_xor(dist, 1, 64);
    dist += __shfl_xor(dist, 2, 64);
    dist += __shfl_xor(dist, 4, 64);

    if (l == 0) {
        out[n] = weight[0] * dist;
    }
}

extern "C" void kernel_launch(void* const* d_in, const int* in_sizes, int n_in,
                              void* d_out, int out_size, void* d_ws, size_t ws_size,
                              hipStream_t stream) {
    const float* pos    = (const float*)d_in[0];  // link_pos_seq  [B,H,L,3]
    const float* rot    = (const float*)d_in[1];  // link_rot_seq  [B,H,L,3,3]
    const float* off    = (const float*)d_in[2];  // sphere_offsets [L,S,3]
    const float* srad   = (const float*)d_in[3];  // sphere_radii  [L,S]
    const float* oc     = (const float*)d_in[4];  // obj_centers   [O,3]
    const float* orad   = (const float*)d_in[5];  // obj_radii     [O]
    const float* weight = (const float*)d_in[6];  // scalar
    float* out = (float*)d_out;                   // [B,H] = [N]

    constexpr int block = 256;
    constexpr int grid  = (NN * 8) / block;  // 512 blocks

    PrimitiveCollisionCost_19533511262442_kernel<<<grid, block, 0, stream>>>(
        pos, rot, off, srad, oc, orad, weight, out);
}